// Round 8
// baseline (118.762 us; speedup 1.0000x reference)
//
#include <hip/hip_runtime.h>
#include <hip/hip_fp16.h>

// GCN layer on MI355X — CSR-gather, atomic-free CSR build, fp16 MFMA GEMM.
// out[c] = dis[c] * ( sum_{e: dst=c} t2[src_e] + t2[c] ) + bias
// t2[i] = dis[i] * (x @ W)[i], dis[i] = rsqrt(1 + outdeg(i)).
//
// Round-7 post-mortem: all our kernels < 43us (harness ws-fills top the
// profile). Remaining budget ~= gather 30 + build 25-35 + gemm 10 + ~15-20us
// of launch gaps over 9 kernels. This round: (1) gather restructured for 2x
// memory-level parallelism (32 lanes x 8B per row, wave halves process
// even/odd edges, shfl_xor(32) reduce) since r5 profile showed latency-bound
// (VALUBusy 17%, occ 67%); (2) 9 -> 7 launches (k_wt folded into k_scan2,
// k_deg+k_csr merged into k_bucket).

#define EPB 4096  // edges per k_hist/k_part block

typedef _Float16 f16;
typedef f16 f16x4 __attribute__((ext_vector_type(4)));
typedef f16 f16x8 __attribute__((ext_vector_type(8)));
typedef float f32x4 __attribute__((ext_vector_type(4)));

static inline int cdiv(int a, int b) { return (a + b - 1) / b; }

// P1: coarse histograms, transposed layout hist[bin*nblk + blk] (dst) and
// hist[HALF + bin*nblk + blk] (src), HALF = nbins*nblk.
__global__ __launch_bounds__(256) void k_hist(const int* __restrict__ ei, int E,
                                              int* __restrict__ hist, int nblk, int nbins) {
  __shared__ int ha[256], hb[256];
  const int tid = threadIdx.x, blk = blockIdx.x;
  ha[tid] = 0; hb[tid] = 0;
  __syncthreads();
  const int base = blk * EPB;
  for (int i = tid; i < EPB; i += 256) {
    int e = base + i;
    if (e >= E) break;
    int src = ei[e];
    int dst = ei[E + e];
    atomicAdd(&ha[dst >> 8], 1);
    atomicAdd(&hb[src >> 8], 1);
  }
  __syncthreads();
  if (tid < nbins) {
    hist[tid * nblk + blk] = ha[tid];
    hist[nbins * nblk + tid * nblk + blk] = hb[tid];
  }
}

// Hierarchical exclusive scan stage 1 (in place), 1024 elems/block.
// Consumers add partials[idx>>10]; no stage-3 pass.
__global__ __launch_bounds__(256) void k_scan1(int* __restrict__ a,
                                               int* __restrict__ partials, int M) {
  __shared__ int ws[256];
  const int tid = threadIdx.x;
  const int i0 = blockIdx.x * 1024 + tid * 4;
  int v0 = (i0 + 0 < M) ? a[i0 + 0] : 0;
  int v1 = (i0 + 1 < M) ? a[i0 + 1] : 0;
  int v2 = (i0 + 2 < M) ? a[i0 + 2] : 0;
  int v3 = (i0 + 3 < M) ? a[i0 + 3] : 0;
  int tsum = v0 + v1 + v2 + v3;
  ws[tid] = tsum;
  __syncthreads();
#pragma unroll
  for (int off = 1; off < 256; off <<= 1) {
    int add = (tid >= off) ? ws[tid - off] : 0;
    __syncthreads();
    ws[tid] += add;
    __syncthreads();
  }
  int texcl = ws[tid] - tsum;
  if (tid == 255) partials[blockIdx.x] = ws[255];
  if (i0 + 0 < M) a[i0 + 0] = texcl;
  if (i0 + 1 < M) a[i0 + 1] = texcl + v0;
  if (i0 + 2 < M) a[i0 + 2] = texcl + v0 + v1;
  if (i0 + 3 < M) a[i0 + 3] = texcl + v0 + v1 + v2;
}

// Stage 2: single block, nb <= 256 partials, exclusive in place.
// Folded in: W[k][c] fp32 -> WhT[c][k] fp16 (B^T for the MFMA B-operand);
// the 256 threads were idle after the tiny scan anyway.
__global__ __launch_bounds__(256) void k_scan2wt(int* __restrict__ p, int nb,
                                                 const float* __restrict__ W,
                                                 f16* __restrict__ WhT) {
  __shared__ int ws[256];
  const int tid = threadIdx.x;
  int v = (tid < nb) ? p[tid] : 0;
  ws[tid] = v;
  __syncthreads();
#pragma unroll
  for (int off = 1; off < 256; off <<= 1) {
    int add = (tid >= off) ? ws[tid - off] : 0;
    __syncthreads();
    ws[tid] += add;
    __syncthreads();
  }
  if (tid < nb) p[tid] = ws[tid] - v;
#pragma unroll 4
  for (int i = tid; i < 128 * 128; i += 256) {
    int k = i >> 7, c = i & 127;
    WhT[c * 128 + k] = (f16)W[i];
  }
}

// P2: partition edges into coarse buckets. ebA[posA] = (src<<8)|(dst&255)
// (dst-bucketed), ebB[posB] = src&255 (src-bucketed, uchar). Plain stores only.
__global__ __launch_bounds__(256) void k_part(const int* __restrict__ ei, int E,
                                              const int* __restrict__ hist,
                                              const int* __restrict__ partials,
                                              int nblk, int nbins,
                                              int* __restrict__ ebA,
                                              unsigned char* __restrict__ ebB) {
  __shared__ int cA[256], cB[256];
  const int tid = threadIdx.x, blk = blockIdx.x;
  const int HALF = nbins * nblk;
  if (tid < nbins) {
    int ia = tid * nblk + blk;
    int ib = HALF + tid * nblk + blk;
    cA[tid] = hist[ia] + partials[ia >> 10];
    cB[tid] = hist[ib] + partials[ib >> 10] - E;
  }
  __syncthreads();
  const int base = blk * EPB;
  for (int i = tid; i < EPB; i += 256) {
    int e = base + i;
    if (e >= E) break;
    int src = ei[e];
    int dst = ei[E + e];
    int pa = atomicAdd(&cA[dst >> 8], 1);
    ebA[pa] = (src << 8) | (dst & 255);
    int pb = atomicAdd(&cB[src >> 8], 1);
    ebB[pb] = (unsigned char)(src & 255);
  }
}

// P3 merged: per coarse bucket b,
//  phase 1 (deg): fine count of src over ebB bucket -> dis = rsqrt(1+cnt)
//  phase 2 (csr): fine count+scan of dst over ebA bucket -> offs, place srcs
__global__ __launch_bounds__(256) void k_bucket(
    const int* __restrict__ ebA, const unsigned char* __restrict__ ebB,
    const int* __restrict__ hist, const int* __restrict__ partials,
    int nblk, int nbins, int E,
    float* __restrict__ dis, int* __restrict__ offs,
    int* __restrict__ srcs, int N) {
  __shared__ int h[256], tmp[256], cur[256];
  const int tid = threadIdx.x, b = blockIdx.x;
  const int HALF = nbins * nblk;
  const int node = b * 256 + tid;

  // --- phase 1: out-degree -> dis ---
  {
    int i0 = HALF + b * nblk;
    const int bs = hist[i0] + partials[i0 >> 10] - E;
    int be = E;
    if (b + 1 < nbins) {
      int i1 = HALF + (b + 1) * nblk;
      be = hist[i1] + partials[i1 >> 10] - E;
    }
    h[tid] = 0;
    __syncthreads();
    for (int j = bs + tid; j < be; j += 256) atomicAdd(&h[ebB[j]], 1);
    __syncthreads();
    if (node < N) dis[node] = rsqrtf(1.0f + (float)h[tid]);
    __syncthreads();
  }

  // --- phase 2: CSR offs + srcs ---
  {
    int i0 = b * nblk;
    const int bs = hist[i0] + partials[i0 >> 10];
    int be = E;
    if (b + 1 < nbins) {
      int i1 = (b + 1) * nblk;
      be = hist[i1] + partials[i1 >> 10];
    }
    h[tid] = 0;
    __syncthreads();
    for (int j = bs + tid; j < be; j += 256) atomicAdd(&h[ebA[j] & 255], 1);
    __syncthreads();
    int cnt = h[tid];
    tmp[tid] = cnt;
    __syncthreads();
#pragma unroll
    for (int off = 1; off < 256; off <<= 1) {
      int add = (tid >= off) ? tmp[tid - off] : 0;
      __syncthreads();
      tmp[tid] += add;
      __syncthreads();
    }
    int gpos = bs + tmp[tid] - cnt;
    if (node < N) offs[node] = gpos;
    cur[tid] = gpos;
    __syncthreads();
    for (int j = bs + tid; j < be; j += 256) {
      int v = ebA[j];
      int p = atomicAdd(&cur[v & 255], 1);
      srcs[p] = v >> 8;
    }
    if (b == 0 && tid == 0) offs[N] = E;
  }
}

// MFMA GEMM: t2h[r][c] = fp16( dis[r] * sum_k x[r][k] * W[k][c] ).
// 256 thr = 4 waves; wave w owns rows [blk*64 + w*16, +16), all 128 cols.
// Per wave: 8 col-tiles x 4 k-chunks of mfma_f32_16x16x32_f16.
// C/D layout: col = lane&15, row = (lane>>4)*4 + reg  [guide §3, m89].
__global__ __launch_bounds__(256) void k_gemm_mfma(
    const float* __restrict__ x, const f16* __restrict__ WhT,
    const float* __restrict__ dis, __half* __restrict__ t2h, int N) {
  __shared__ __align__(16) f16 cs[4][16][136];  // stride 272B = 17x16B
  const int tid = threadIdx.x;
  const int w = tid >> 6, l = tid & 63;
  const int l15 = l & 15, lg = l >> 4;
  const int wr0 = blockIdx.x * 64 + w * 16;
  const int arow = wr0 + l15;
  const bool avalid = arow < N;

  f32x4 acc[8];
#pragma unroll
  for (int ct = 0; ct < 8; ++ct) acc[ct] = (f32x4){0.f, 0.f, 0.f, 0.f};

#pragma unroll
  for (int kc = 0; kc < 4; ++kc) {
    f16x8 af;
    if (avalid) {
      const float4* ap = (const float4*)(x + (size_t)arow * 128 + kc * 32 + lg * 8);
      float4 a0 = ap[0], a1 = ap[1];
      af[0] = (f16)a0.x; af[1] = (f16)a0.y; af[2] = (f16)a0.z; af[3] = (f16)a0.w;
      af[4] = (f16)a1.x; af[5] = (f16)a1.y; af[6] = (f16)a1.z; af[7] = (f16)a1.w;
    } else {
#pragma unroll
      for (int j = 0; j < 8; ++j) af[j] = (f16)0.f;
    }
#pragma unroll
    for (int ct = 0; ct < 8; ++ct) {
      f16x8 bf = *(const f16x8*)(WhT + (ct * 16 + l15) * 128 + kc * 32 + lg * 8);
      acc[ct] = __builtin_amdgcn_mfma_f32_16x16x32_f16(af, bf, acc[ct], 0, 0, 0);
    }
  }

  // scale rows by dis and stash (transposed per-wave) in LDS
  float d4[4];
#pragma unroll
  for (int j = 0; j < 4; ++j) {
    int r = wr0 + lg * 4 + j;
    d4[j] = (r < N) ? dis[r] : 0.f;
  }
#pragma unroll
  for (int ct = 0; ct < 8; ++ct)
#pragma unroll
    for (int j = 0; j < 4; ++j)
      cs[w][lg * 4 + j][ct * 16 + l15] = (f16)(d4[j] * acc[ct][j]);
  __syncthreads();

  // coalesced write-out: 4 iters x 64 lanes x 16B
#pragma unroll
  for (int it = 0; it < 4; ++it) {
    int t = it * 64 + l;
    int row = t >> 4, seg = t & 15;
    int gr = wr0 + row;
    if (gr < N)
      *(f16x8*)((f16*)t2h + (size_t)gr * 128 + seg * 8) = *(const f16x8*)&cs[w][row][seg * 8];
  }
}

// One 64-lane wave per node. 32 lanes x 8B (f16x4) cover a 256B t2h row;
// wave halves process even/odd edges (2x rows in flight vs r7), then
// cross-half shfl_xor(32) reduce; half 0 writes the fp32 row (16B/lane).
__global__ __launch_bounds__(256) void k_gather(
    const int* __restrict__ offs, const int* __restrict__ srcs,
    const __half* __restrict__ t2h, const float* __restrict__ dis,
    const float* __restrict__ bias, float* __restrict__ out, int N) {
  const int node = blockIdx.x * 4 + (threadIdx.x >> 6);
  const int l = threadIdx.x & 63;
  if (node >= N) return;
  const int half = l >> 5, sl = l & 31;

  const int s = offs[node];
  const int e = offs[node + 1];
  const f16x4* t2v = (const f16x4*)t2h;  // row stride 32 (128 f16 / 4)

  float4 acc = make_float4(0.f, 0.f, 0.f, 0.f);
  if (half == 0) {  // self loop, counted once
    f16x4 v = t2v[(size_t)node * 32 + sl];
    acc.x = (float)v[0]; acc.y = (float)v[1]; acc.z = (float)v[2]; acc.w = (float)v[3];
  }

  int j = s + half;
  for (; j + 6 < e; j += 8) {  // 4 edges per half in flight
    int s0 = srcs[j], s1 = srcs[j + 2], s2 = srcs[j + 4], s3 = srcs[j + 6];
    f16x4 v0 = t2v[(size_t)s0 * 32 + sl];
    f16x4 v1 = t2v[(size_t)s1 * 32 + sl];
    f16x4 v2 = t2v[(size_t)s2 * 32 + sl];
    f16x4 v3 = t2v[(size_t)s3 * 32 + sl];
    acc.x += ((float)v0[0] + (float)v1[0]) + ((float)v2[0] + (float)v3[0]);
    acc.y += ((float)v0[1] + (float)v1[1]) + ((float)v2[1] + (float)v3[1]);
    acc.z += ((float)v0[2] + (float)v1[2]) + ((float)v2[2] + (float)v3[2]);
    acc.w += ((float)v0[3] + (float)v1[3]) + ((float)v2[3] + (float)v3[3]);
  }
  for (; j < e; j += 2) {
    f16x4 v = t2v[(size_t)srcs[j] * 32 + sl];
    acc.x += (float)v[0]; acc.y += (float)v[1];
    acc.z += (float)v[2]; acc.w += (float)v[3];
  }

  // cross-half reduction (lane ^ 32)
  acc.x += __shfl_xor(acc.x, 32);
  acc.y += __shfl_xor(acc.y, 32);
  acc.z += __shfl_xor(acc.z, 32);
  acc.w += __shfl_xor(acc.w, 32);

  if (half == 0) {
    const float dn = dis[node];
    const float4 b = ((const float4*)bias)[sl];
    float4 r;
    r.x = dn * acc.x + b.x;
    r.y = dn * acc.y + b.y;
    r.z = dn * acc.z + b.z;
    r.w = dn * acc.w + b.w;
    ((float4*)(out + (size_t)node * 128))[sl] = r;
  }
}

extern "C" void kernel_launch(void* const* d_in, const int* in_sizes, int n_in,
                              void* d_out, int out_size, void* d_ws, size_t ws_size,
                              hipStream_t stream) {
  const float* x = (const float*)d_in[0];
  const int* ei = (const int*)d_in[1];   // int64 in reference, int32 on device: [2,E] flat
  const float* W = (const float*)d_in[2];
  const float* bias = (const float*)d_in[3];
  float* out = (float*)d_out;

  const int N = in_sizes[0] / 128;
  const int E = in_sizes[1] / 2;
  const int NBLK = cdiv(E, EPB);    // edge blocks (196)
  const int NBINS = cdiv(N, 256);   // coarse node buckets (196)
  const int M = 2 * NBINS * NBLK;   // concatenated hist length
  const int NB1 = cdiv(M, 1024);    // scan stage-1 blocks (<=256 required)

  // Workspace. Overlay region (hist|partials|ebA|ebB ~4.4MB) aliases t2h
  // (12.8MB): dead before k_gemm_mfma writes t2h. Total ws use ~16.5 MB.
  __half* t2h = (__half*)d_ws;
  int* hist = (int*)d_ws;                      // [M]
  int* partials = hist + M;                    // [<=256]
  int* ebA = partials + 256;                   // [E]  (src<<8)|(dst&255), dst-bucketed
  unsigned char* ebB = (unsigned char*)(ebA + E);  // [E] src&255, src-bucketed
  float* dis = (float*)(t2h + (size_t)N * 128);    // [N]
  int* offs = (int*)(dis + N);                 // [N+1]
  int* srcs = offs + (N + 1);                  // [E]
  f16* WhT = (f16*)(srcs + E);                 // [128*128] fp16 B^T

  k_hist<<<NBLK, 256, 0, stream>>>(ei, E, hist, NBLK, NBINS);
  k_scan1<<<NB1, 256, 0, stream>>>(hist, partials, M);
  k_scan2wt<<<1, 256, 0, stream>>>(partials, NB1, W, WhT);
  k_part<<<NBLK, 256, 0, stream>>>(ei, E, hist, partials, NBLK, NBINS, ebA, ebB);
  k_bucket<<<NBINS, 256, 0, stream>>>(ebA, ebB, hist, partials, NBLK, NBINS, E,
                                      dis, offs, srcs, N);
  k_gemm_mfma<<<cdiv(N, 64), 256, 0, stream>>>(x, WhT, dis, t2h, N);
  k_gather<<<cdiv(N, 4), 256, 0, stream>>>(offs, srcs, t2h, dis, bias, out, N);
}